// Round 5
// baseline (388.591 us; speedup 1.0000x reference)
//
#include <hip/hip_runtime.h>
#include <hip/hip_bf16.h>
#include <cstdint>

typedef __bf16 bf16;
typedef __bf16 bf16x8 __attribute__((ext_vector_type(8)));
typedef float  f32x4  __attribute__((ext_vector_type(4)));

#define B_   2
#define T_   2048
#define D_   2048
#define H_   16
#define HD_  128

// async global->LDS, 16 B per lane (m97: the 874 TF enabler).
// LDS dest must be wave-uniform base + lane*16 -> lanes stay contiguous in
// physical-slot order; we permute the GLOBAL side per-lane for XOR swizzles.
typedef __attribute__((address_space(3))) void       lds_void;
typedef __attribute__((address_space(1))) const void gbl_void;
__device__ __forceinline__ void glds16(const bf16* g, bf16* l) {
    __builtin_amdgcn_global_load_lds((gbl_void*)g, (lds_void*)l, 16, 0, 0);
}

// ---------------------------------------------------------------------------
// fp32 -> bf16 pre-convert (grid-stride, float4 -> 4x bf16 pack)
// ---------------------------------------------------------------------------
__device__ __forceinline__ ushort4 cvt4(const float4 v) {
    union { bf16 h[4]; ushort4 u; } pk;
    pk.h[0] = (bf16)v.x; pk.h[1] = (bf16)v.y;
    pk.h[2] = (bf16)v.z; pk.h[3] = (bf16)v.w;
    return pk.u;
}

__global__ __launch_bounds__(256) void convert_xw_kernel(
    const float* __restrict__ x, const float* __restrict__ wqkv,
    bf16* __restrict__ xb, bf16* __restrict__ wqkvb)
{
    const int NX = (B_ * T_ * D_) / 4;          // 2,097,152 float4
    const int NT = NX + (3 * D_ * D_) / 4;      // + 3,145,728
    for (int g = blockIdx.x * blockDim.x + threadIdx.x; g < NT;
         g += gridDim.x * blockDim.x) {
        if (g < NX) ((ushort4*)xb)[g]      = cvt4(((const float4*)x)[g]);
        else        ((ushort4*)wqkvb)[g-NX] = cvt4(((const float4*)wqkv)[g-NX]);
    }
}

__global__ __launch_bounds__(256) void convert_wo_kernel(
    const float* __restrict__ wo, bf16* __restrict__ wob)
{
    const int N = (D_ * D_) / 4;                // 1,048,576 float4
    for (int g = blockIdx.x * blockDim.x + threadIdx.x; g < N;
         g += gridDim.x * blockDim.x)
        ((ushort4*)wob)[g] = cvt4(((const float4*)wo)[g]);
}

// ---------------------------------------------------------------------------
// m97-style NT-GEMM core with XOR-swizzled LDS: C[128x128], A[M][K], W[N][K]
// bf16 K-major, global_load_lds width-16 staging into [128][64] tiles.
// ---------------------------------------------------------------------------
__device__ __forceinline__ void gemm_core_glds(
    const bf16* __restrict__ A, const bf16* __restrict__ W, int K,
    int bm, int bn, int tid, f32x4 (&acc)[4][4],
    bf16* lds_a, bf16* lds_b)
{
    const int lane = tid & 63, quad = lane >> 4, lcol = lane & 15;
    const int wave = tid >> 6;
    const int wm = (wave >> 1) * 64, wn2 = (wave & 1) * 32;
    const int sw = lcol & 7;                          // read-side swizzle key
    const int sr = tid >> 3, pc = tid & 7;            // staging row / physical chunk
    const int sc = (pc ^ (sr & 7)) * 8;               // logical col group fetched
    const bf16* abase = A + (size_t)(bm * 128 + sr) * K + sc;
    const bf16* bbase = W + (size_t)(bn * 128 + sr) * K + sc;
    bf16* la = lds_a + sr * 64 + pc * 8;              // = lds_a + tid*8 elems
    bf16* lb = lds_b + sr * 64 + pc * 8;

    for (int k0 = 0; k0 < K; k0 += 64) {
        __syncthreads();
#pragma unroll
        for (int p = 0; p < 4; p++) {                 // (sr+32p)&7 == sr&7
            glds16(abase + k0 + (size_t)32 * p * K, la + 2048 * p);
            glds16(bbase + k0 + (size_t)32 * p * K, lb + 2048 * p);
        }
        __syncthreads();
#pragma unroll
        for (int kk = 0; kk < 2; kk++) {
            bf16x8 af[4], bfr[4];
#pragma unroll
            for (int i = 0; i < 4; i++)
                af[i] = *(const bf16x8*)&lds_a[(wm + i * 16 + lcol) * 64 +
                                               (((kk * 4 + quad) ^ sw) * 8)];
#pragma unroll
            for (int j = 0; j < 4; j++) {
                const int row = wn2 + (j & 1) * 16 + (j >> 1) * 64 + lcol;
                bfr[j] = *(const bf16x8*)&lds_b[row * 64 +
                                                (((kk * 4 + quad) ^ sw) * 8)];
            }
#pragma unroll
            for (int i = 0; i < 4; i++)
#pragma unroll
                for (int j = 0; j < 4; j++)
                    acc[i][j] = __builtin_amdgcn_mfma_f32_16x16x32_bf16(af[i], bfr[j], acc[i][j], 0, 0, 0);
        }
    }
}

// ---------------------------------------------------------------------------
// QKV projection (bf16 in via pre-convert) + fused RoPE + head scatter:
//   q,k -> [bh][t][d] with rotary applied;  v -> vT[bh][d][t]
// vT keys are PI-PERMUTED within each 64-t block: phys(t) = (t&15)*4 + (t>>4)
// -> attn's P-store is a packed ushort4 and V reads stay bf16x8-contiguous.
// ---------------------------------------------------------------------------
__global__ __launch_bounds__(256) void qkv_gemm_kernel(
    const bf16* __restrict__ xb, const bf16* __restrict__ wqkvb,
    const float* __restrict__ bias,
    bf16* __restrict__ qh, bf16* __restrict__ kh, bf16* __restrict__ vT)
{
    __shared__ bf16 lds_a[128 * 64];
    __shared__ bf16 lds_b[128 * 64];
    const int tid = threadIdx.x;
    const int bm = blockIdx.y, bn = blockIdx.x;
    const int lane = tid & 63, quad = lane >> 4, lcol = lane & 15;
    const int wave = tid >> 6;
    const int wm = (wave >> 1) * 64, wn2 = (wave & 1) * 32;

    f32x4 acc[4][4];
    const f32x4 z = {0.f, 0.f, 0.f, 0.f};
#pragma unroll
    for (int i = 0; i < 4; i++)
#pragma unroll
        for (int j = 0; j < 4; j++) acc[i][j] = z;

    gemm_core_glds(xb, wqkvb, D_, bm, bn, tid, acc, lds_a, lds_b);

    const int n0 = bn * 128;
    const int part = bn / 16;            // 0=q 1=k 2=v (block-uniform)
    const int h = bn & 15;
    const int mb0 = bm * 128 + wm;       // 64-aligned -> one batch, one 64-blk

    if (part < 2) {
        bf16* dst = (part == 0) ? qh : kh;
#pragma unroll
        for (int i = 0; i < 4; i++) {
#pragma unroll
            for (int jp = 0; jp < 2; jp++) {
                const int d1 = wn2 + jp * 16 + lcol;       // 0..63
                const float invf = __expf(-0.14391156831212787f * (float)d1);
                const float b1 = bias[n0 + d1];
                const float b2 = bias[n0 + d1 + 64];
#pragma unroll
                for (int r = 0; r < 4; r++) {
                    const int m = mb0 + i * 16 + quad * 4 + r;
                    const int bb = m >> 11, t = m & (T_ - 1);
                    const float x1 = acc[i][jp][r] + b1;       // d1
                    const float x2 = acc[i][jp + 2][r] + b2;   // d1 + 64
                    float s, c;
                    __sincosf((float)t * invf, &s, &c);
                    const size_t rowo = ((size_t)(bb * H_ + h) * T_ + t) * HD_;
                    dst[rowo + d1]      = (bf16)(x1 * c - x2 * s);
                    dst[rowo + d1 + 64] = (bf16)(x1 * s + x2 * c);
                }
            }
        }
    } else {
        const int bb = mb0 >> 11, t64 = mb0 & (T_ - 1);   // 64-aligned t base
        const int bh = bb * H_ + h;
#pragma unroll
        for (int j = 0; j < 4; j++) {
            const int d = wn2 + (j & 1) * 16 + (j >> 1) * 64 + lcol;
            const float bv = bias[n0 + d];
            bf16* vdst = &vT[((size_t)bh * HD_ + d) * T_ + t64];
#pragma unroll
            for (int r = 0; r < 4; r++) {
                union { bf16 hh[4]; ushort4 u; } pk;
#pragma unroll
                for (int i = 0; i < 4; i++) pk.hh[i] = (bf16)(acc[i][j][r] + bv);
                // phys(t=i*16+quad*4+r) = (quad*4+r)*4 + i  -> contiguous in i
                *(ushort4*)&vdst[(quad * 4 + r) * 4] = pk.u;
            }
        }
    }
}

// ---------------------------------------------------------------------------
// Flash attention (causal), R10: R8 inner loop (32 rows/wave, the 2x-better
// LDS ratio) + UNIFORM-WORK blocks (the R8/R9 scheduling fix).
//
// LDS-floor arithmetic (measured-backed): 16-rows/wave shape floor ~45us
// (R7 measured ~100 -> 45% util); 32-rows/wave floor ~24.5us (R8 measured
// ~118 -> 21% util, killed by static 2/CU-exact grid + work variance).
// Static dispatch order is undefined (R9's LPT flopped), so make every
// block IDENTICAL: block = q-tile pair (qt, 15-qt), steps = (2qt+2) +
// (2(15-qt)+2) = 36 for all. Grid = 32bh x 8 pairs = 256 = 1 block/CU,
// zero tail. Same bh for both tiles -> K/V dbuf staging runs as one flat
// 36-step sequence across the tile switch (buffer parity continuous).
// Mid-loop epilogue at s==ktA writes tile A's ctx, resets acc, reloads Q.
// launch_bounds(256,1): 1 block/CU -> full VGPR budget, no spills.
// LDS: 2*16KB (K) + 2*16KB (V) + 16KB (P) = 80KB.
// ---------------------------------------------------------------------------
__global__ __launch_bounds__(256, 1) void attn_kernel(
    const bf16* __restrict__ qh, const bf16* __restrict__ kh,
    const bf16* __restrict__ vT, bf16* __restrict__ ctx)
{
    __shared__ bf16 lds_k[2][64 * 128];   // [key][d], XOR-swizzled
    __shared__ bf16 lds_v[2][128 * 64];   // [d][phys-key], XOR-swizzled
    __shared__ bf16 lds_p[128 * 64];      // P (phys-key order), wave-private rows
    const int tid = threadIdx.x;
    const int id = blockIdx.x;            // 256 = 32 bh x 8 pairs
    const int bh = id & 31;
    const int qp = id >> 5;               // 0..7
    const int qtA = 15 - qp;              // heavy tile (8..15)
    const int qtB = qp;                   // light tile (0..7)
    const int ktA = 2 * qtA + 2;          // ktA + ktB == 36 (uniform)
    const int lane = tid & 63, quad = lane >> 4, lcol = lane & 15;
    const int wave = tid >> 6;
    const int wq0 = wave * 32;
    const float scale2 = 0.08838834764831845f * 1.4426950408889634f;
    const int b = bh >> 4, h = bh & 15;

    const bf16* kbase = kh + (size_t)bh * T_ * HD_;
    const bf16* vbase = vT + (size_t)bh * HD_ * T_;

    // K staging: row srow+16p, chunk tid&15; src col chunk ^ (row&15).
    const int ksrow = tid >> 4;                        // 0..15
    const bf16* kstage = kbase + (size_t)ksrow * HD_ + (((tid & 15) ^ ksrow) << 3);
    // V staging: d row vsd+32p, chunk tid&7; src key chunk ^ (d&7).
    const int vsd = tid >> 3;                          // 0..31
    const bf16* vstage = vbase + (size_t)vsd * T_ + (((tid & 7) ^ (vsd & 7)) << 3);

    int q0 = qtA * 128;

    bf16x8 qf[2][4];
    auto load_q = [&](int q0_) {
#pragma unroll
        for (int i = 0; i < 2; i++)
#pragma unroll
            for (int kk = 0; kk < 4; kk++)
                qf[i][kk] = *(const bf16x8*)&qh[((size_t)bh * T_ + q0_ + wq0 + i * 16 + lcol) * HD_ +
                                                kk * 32 + quad * 8];
    };
    load_q(q0);

    f32x4 o[2][8];
    const f32x4 z = {0.f, 0.f, 0.f, 0.f};
#pragma unroll
    for (int i = 0; i < 2; i++)
#pragma unroll
        for (int jd = 0; jd < 8; jd++) o[i][jd] = z;
    float l_part[2][4];
#pragma unroll
    for (int i = 0; i < 2; i++)
#pragma unroll
        for (int r = 0; r < 4; r++) l_part[i][r] = 0.f;

    auto do_epilogue = [&](int q0_) {
        float inv_l[2][4];
#pragma unroll
        for (int i = 0; i < 2; i++)
#pragma unroll
            for (int r = 0; r < 4; r++) {
                float rs = l_part[i][r];
#pragma unroll
                for (int off = 1; off < 16; off <<= 1)
                    rs += __shfl_xor(rs, off);
                inv_l[i][r] = 1.0f / rs;
            }
#pragma unroll
        for (int i = 0; i < 2; i++) {
#pragma unroll
            for (int r = 0; r < 4; r++) {
                const int t = q0_ + wq0 + i * 16 + quad * 4 + r;
#pragma unroll
                for (int jd = 0; jd < 8; jd++)
                    ctx[((size_t)(b * T_ + t)) * D_ + h * HD_ + jd * 16 + lcol] =
                        (bf16)(o[i][jd][r] * inv_l[i][r]);
            }
        }
    };

    int wrow_min = q0 + wq0;              // wave's q-row span (current tile)
    int wrow_max = wrow_min + 31;

    // prologue: stage key-tile 0 into buf 0
#pragma unroll
    for (int p = 0; p < 4; p++) {
        glds16(kstage + (size_t)16 * p * HD_, &lds_k[0][tid * 8 + p * 2048]);
        glds16(vstage + (size_t)32 * p * T_, &lds_v[0][tid * 8 + p * 2048]);
    }

    for (int s = 0; s < 36; s++) {
        __syncthreads();                  // stage(s) landed; buf^1 reads done
        if (s + 1 < 36) {                 // prefetch next key-tile (flat seq)
            const int kn = (s + 1 < ktA) ? (s + 1) : (s + 1 - ktA);
            const bf16* ks = kstage + (size_t)kn * 64 * HD_;
            const bf16* vs = vstage + kn * 64;
            bf16* lkd = &lds_k[(s + 1) & 1][tid * 8];
            bf16* lvd = &lds_v[(s + 1) & 1][tid * 8];
#pragma unroll
            for (int p = 0; p < 4; p++) {
                glds16(ks + (size_t)16 * p * HD_, lkd + p * 2048);
                glds16(vs + (size_t)32 * p * T_, lvd + p * 2048);
            }
        }
        if (s == ktA) {                   // tile switch: A -> B (block-uniform)
            do_epilogue(q0);
            q0 = qtB * 128;
            load_q(q0);
#pragma unroll
            for (int i = 0; i < 2; i++)
#pragma unroll
                for (int jd = 0; jd < 8; jd++) o[i][jd] = z;
#pragma unroll
            for (int i = 0; i < 2; i++)
#pragma unroll
                for (int r = 0; r < 4; r++) l_part[i][r] = 0.f;
            wrow_min = q0 + wq0;
            wrow_max = wrow_min + 31;
        }
        const int kt = (s < ktA) ? s : (s - ktA);
        // per-wave: skip tiles entirely above this wave's diagonal
        if (kt * 64 > wrow_max) continue; // next iter's barrier keeps sync
        const bool needmask = (kt * 64 + 63 > wrow_min);
        const bf16* lk = lds_k[s & 1];
        const bf16* lv = lds_v[s & 1];

        // ---- QK^T: K B-fragments from swizzled LDS ----
        f32x4 s_acc[2][4];
#pragma unroll
        for (int i = 0; i < 2; i++)
#pragma unroll
            for (int j = 0; j < 4; j++) s_acc[i][j] = z;
        __builtin_amdgcn_s_setprio(1);
#pragma unroll
        for (int kk = 0; kk < 4; kk++) {
#pragma unroll
            for (int j = 0; j < 4; j++) {
                const bf16x8 bk = *(const bf16x8*)&lk[(j * 16 + lcol) * 128 +
                                        (((kk * 4 + quad) ^ lcol) << 3)];
#pragma unroll
                for (int i = 0; i < 2; i++)
                    s_acc[i][j] = __builtin_amdgcn_mfma_f32_16x16x32_bf16(qf[i][kk], bk, s_acc[i][j], 0, 0, 0);
            }
        }
        __builtin_amdgcn_s_setprio(0);

        // ---- no-max softmax; packed P store in pi-permuted key order ----
#pragma unroll
        for (int i = 0; i < 2; i++) {
#pragma unroll
            for (int r = 0; r < 4; r++) {
                const int prow = wq0 + i * 16 + quad * 4 + r;  // P row (q-local)
                const int qrow = q0 + prow;                    // global q row
                union { bf16 hh[4]; ushort4 u; } pk;
                float lp = 0.f;
#pragma unroll
                for (int j = 0; j < 4; j++) {
                    float p = exp2f(fmaf(s_acc[i][j][r], scale2, -16.0f));
                    if (needmask) {
                        const int kcol = kt * 64 + j * 16 + lcol;
                        p = (kcol > qrow) ? 0.f : p;
                    }
                    lp += p;
                    pk.hh[j] = (bf16)p;      // phys key = lcol*4 + j
                }
                l_part[i][r] += lp;
                *(ushort4*)&lds_p[prow * 64 + ((lcol * 4) ^ ((prow & 7) << 3))] = pk.u;
            }
        }

        // ---- PV: P and V both from LDS (short, stall-free path) ----
#pragma unroll
        for (int kk2 = 0; kk2 < 2; kk2++) {
            bf16x8 pf[2], vf[8];
#pragma unroll
            for (int i = 0; i < 2; i++) {
                const int prow = wq0 + i * 16 + lcol;
                pf[i] = *(const bf16x8*)&lds_p[prow * 64 +
                            ((kk2 * 32 + quad * 8) ^ ((lcol & 7) << 3))];
            }
#pragma unroll
            for (int jd = 0; jd < 8; jd++) {
                const int d = jd * 16 + lcol;
                vf[jd] = *(const bf16x8*)&lv[d * 64 +
                              (((kk2 * 4 + quad) ^ (lcol & 7)) << 3)];
            }
            __builtin_amdgcn_s_setprio(1);
#pragma unroll
            for (int i = 0; i < 2; i++)
#pragma unroll
                for (int jd = 0; jd < 8; jd++)
                    o[i][jd] = __builtin_amdgcn_mfma_f32_16x16x32_bf16(pf[i], vf[jd], o[i][jd], 0, 0, 0);
            __builtin_amdgcn_s_setprio(0);
        }
    }

    do_epilogue(q0);                      // tile B epilogue
}

// ---------------------------------------------------------------------------
// Output projection: out = ctx @ Wo^T + bo  (bf16 x bf16 -> fp32 out)
// ---------------------------------------------------------------------------
__global__ __launch_bounds__(256) void proj_gemm_kernel(
    const bf16* __restrict__ ctx, const bf16* __restrict__ wob,
    const float* __restrict__ bias, float* __restrict__ out)
{
    __shared__ bf16 lds_a[128 * 64];
    __shared__ bf16 lds_b[128 * 64];
    const int tid = threadIdx.x;
    const int bm = blockIdx.y, bn = blockIdx.x;
    const int lane = tid & 63, quad = lane >> 4, lcol = lane & 15;
    const int wave = tid >> 6;
    const int wm = (wave >> 1) * 64, wn2 = (wave & 1) * 32;

    f32x4 acc[4][4];
    const f32x4 z = {0.f, 0.f, 0.f, 0.f};
#pragma unroll
    for (int i = 0; i < 4; i++)
#pragma unroll
        for (int j = 0; j < 4; j++) acc[i][j] = z;

    gemm_core_glds(ctx, wob, D_, bm, bn, tid, acc, lds_a, lds_b);

    const int n0 = bn * 128;
#pragma unroll
    for (int i = 0; i < 4; i++) {
#pragma unroll
        for (int j = 0; j < 4; j++) {
            const int n = n0 + wn2 + (j & 1) * 16 + (j >> 1) * 64 + lcol;
            const float bv = bias[n];
#pragma unroll
            for (int r = 0; r < 4; r++) {
                const int m = bm * 128 + wm + i * 16 + quad * 4 + r;
                out[(size_t)m * D_ + n] = acc[i][j][r] + bv;
            }
        }
    }
}

extern "C" void kernel_launch(void* const* d_in, const int* in_sizes, int n_in,
                              void* d_out, int out_size, void* d_ws, size_t ws_size,
                              hipStream_t stream)
{
    const float* x    = (const float*)d_in[0];
    const float* Wqkv = (const float*)d_in[1];
    const float* bqkv = (const float*)d_in[2];
    const float* Wo   = (const float*)d_in[3];
    const float* bo   = (const float*)d_in[4];
    // d_in[5] = mask — causal, computed analytically in-kernel.
    float* out = (float*)d_out;

    const size_t HT = (size_t)B_ * H_ * T_ * HD_;   // 8,388,608 elems
    // d_ws (67.1 MB, proven size): [xb|ctx][qh|wob][kh][vT]
    bf16* xb   = (bf16*)d_ws;
    bf16* qh   = xb + HT;
    bf16* kh   = qh + HT;
    bf16* vT   = kh + HT;
    bf16* ctx  = xb;             // xb dead after qkv gemm
    bf16* wob  = qh;             // qh dead after attn
    // d_out (33.55 MB fp32): holds bf16 Wqkv (25.2 MB) until proj overwrites
    bf16* wqkvb = (bf16*)d_out;

    // 1) fp32 -> bf16 pre-convert of x and Wqkv
    convert_xw_kernel<<<2560, 256, 0, stream>>>(x, Wqkv, xb, wqkvb);
    // 2) QKV projection + fused RoPE + head scatter (vT pi-permuted keys)
    qkv_gemm_kernel<<<dim3(48, 32), 256, 0, stream>>>(xb, wqkvb, bqkv, qh, kh, vT);
    // 3) causal flash attention -> ctx: 256 uniform blocks, each = q-tile
    //    pair (qt, 15-qt) => 36 key-tile steps per block, zero tail
    attn_kernel<<<256, 256, 0, stream>>>(qh, kh, vT, ctx);
    // 4) Wo -> bf16 into dead qh region
    convert_wo_kernel<<<1024, 256, 0, stream>>>(Wo, wob);
    // 5) output projection -> fp32 out (overwrites wqkvb region)
    proj_gemm_kernel<<<dim3(16, 32), 256, 0, stream>>>(ctx, wob, bo, out);
}

// Round 6
// 354.575 us; speedup vs baseline: 1.0959x; 1.0959x over previous
//
#include <hip/hip_runtime.h>
#include <hip/hip_bf16.h>
#include <cstdint>

typedef __bf16 bf16;
typedef __bf16 bf16x8 __attribute__((ext_vector_type(8)));
typedef float  f32x4  __attribute__((ext_vector_type(4)));

#define B_   2
#define T_   2048
#define D_   2048
#define H_   16
#define HD_  128

// async global->LDS, 16 B per lane (m97: the 874 TF enabler).
// LDS dest must be wave-uniform base + lane*16 -> lanes stay contiguous in
// physical-slot order; we permute the GLOBAL side per-lane for XOR swizzles.
typedef __attribute__((address_space(3))) void       lds_void;
typedef __attribute__((address_space(1))) const void gbl_void;
__device__ __forceinline__ void glds16(const bf16* g, bf16* l) {
    __builtin_amdgcn_global_load_lds((gbl_void*)g, (lds_void*)l, 16, 0, 0);
}

// ---------------------------------------------------------------------------
// fp32 -> bf16 pre-convert (grid-stride, float4 -> 4x bf16 pack)
// ---------------------------------------------------------------------------
__device__ __forceinline__ ushort4 cvt4(const float4 v) {
    union { bf16 h[4]; ushort4 u; } pk;
    pk.h[0] = (bf16)v.x; pk.h[1] = (bf16)v.y;
    pk.h[2] = (bf16)v.z; pk.h[3] = (bf16)v.w;
    return pk.u;
}

__global__ __launch_bounds__(256) void convert_xw_kernel(
    const float* __restrict__ x, const float* __restrict__ wqkv,
    bf16* __restrict__ xb, bf16* __restrict__ wqkvb)
{
    const int NX = (B_ * T_ * D_) / 4;          // 2,097,152 float4
    const int NT = NX + (3 * D_ * D_) / 4;      // + 3,145,728
    for (int g = blockIdx.x * blockDim.x + threadIdx.x; g < NT;
         g += gridDim.x * blockDim.x) {
        if (g < NX) ((ushort4*)xb)[g]      = cvt4(((const float4*)x)[g]);
        else        ((ushort4*)wqkvb)[g-NX] = cvt4(((const float4*)wqkv)[g-NX]);
    }
}

__global__ __launch_bounds__(256) void convert_wo_kernel(
    const float* __restrict__ wo, bf16* __restrict__ wob)
{
    const int N = (D_ * D_) / 4;                // 1,048,576 float4
    for (int g = blockIdx.x * blockDim.x + threadIdx.x; g < N;
         g += gridDim.x * blockDim.x)
        ((ushort4*)wob)[g] = cvt4(((const float4*)wo)[g]);
}

// ---------------------------------------------------------------------------
// m97-style NT-GEMM core with XOR-swizzled LDS: C[128x128], A[M][K], W[N][K]
// bf16 K-major, global_load_lds width-16 staging into [128][64] tiles.
// ---------------------------------------------------------------------------
__device__ __forceinline__ void gemm_core_glds(
    const bf16* __restrict__ A, const bf16* __restrict__ W, int K,
    int bm, int bn, int tid, f32x4 (&acc)[4][4],
    bf16* lds_a, bf16* lds_b)
{
    const int lane = tid & 63, quad = lane >> 4, lcol = lane & 15;
    const int wave = tid >> 6;
    const int wm = (wave >> 1) * 64, wn2 = (wave & 1) * 32;
    const int sw = lcol & 7;                          // read-side swizzle key
    const int sr = tid >> 3, pc = tid & 7;            // staging row / physical chunk
    const int sc = (pc ^ (sr & 7)) * 8;               // logical col group fetched
    const bf16* abase = A + (size_t)(bm * 128 + sr) * K + sc;
    const bf16* bbase = W + (size_t)(bn * 128 + sr) * K + sc;
    bf16* la = lds_a + sr * 64 + pc * 8;              // = lds_a + tid*8 elems
    bf16* lb = lds_b + sr * 64 + pc * 8;

    for (int k0 = 0; k0 < K; k0 += 64) {
        __syncthreads();
#pragma unroll
        for (int p = 0; p < 4; p++) {                 // (sr+32p)&7 == sr&7
            glds16(abase + k0 + (size_t)32 * p * K, la + 2048 * p);
            glds16(bbase + k0 + (size_t)32 * p * K, lb + 2048 * p);
        }
        __syncthreads();
#pragma unroll
        for (int kk = 0; kk < 2; kk++) {
            bf16x8 af[4], bfr[4];
#pragma unroll
            for (int i = 0; i < 4; i++)
                af[i] = *(const bf16x8*)&lds_a[(wm + i * 16 + lcol) * 64 +
                                               (((kk * 4 + quad) ^ sw) * 8)];
#pragma unroll
            for (int j = 0; j < 4; j++) {
                const int row = wn2 + (j & 1) * 16 + (j >> 1) * 64 + lcol;
                bfr[j] = *(const bf16x8*)&lds_b[row * 64 +
                                                (((kk * 4 + quad) ^ sw) * 8)];
            }
#pragma unroll
            for (int i = 0; i < 4; i++)
#pragma unroll
                for (int j = 0; j < 4; j++)
                    acc[i][j] = __builtin_amdgcn_mfma_f32_16x16x32_bf16(af[i], bfr[j], acc[i][j], 0, 0, 0);
        }
    }
}

// ---------------------------------------------------------------------------
// QKV projection (bf16 in via pre-convert) + fused RoPE + head scatter:
//   q,k -> [bh][t][d] with rotary applied;  v -> vT[bh][d][t]
// vT keys are PI-PERMUTED within each 64-t block: phys(t) = (t&15)*4 + (t>>4)
// -> attn's P-store is a packed ushort4 and V reads stay bf16x8-contiguous.
// ---------------------------------------------------------------------------
__global__ __launch_bounds__(256) void qkv_gemm_kernel(
    const bf16* __restrict__ xb, const bf16* __restrict__ wqkvb,
    const float* __restrict__ bias,
    bf16* __restrict__ qh, bf16* __restrict__ kh, bf16* __restrict__ vT)
{
    __shared__ bf16 lds_a[128 * 64];
    __shared__ bf16 lds_b[128 * 64];
    const int tid = threadIdx.x;
    const int bm = blockIdx.y, bn = blockIdx.x;
    const int lane = tid & 63, quad = lane >> 4, lcol = lane & 15;
    const int wave = tid >> 6;
    const int wm = (wave >> 1) * 64, wn2 = (wave & 1) * 32;

    f32x4 acc[4][4];
    const f32x4 z = {0.f, 0.f, 0.f, 0.f};
#pragma unroll
    for (int i = 0; i < 4; i++)
#pragma unroll
        for (int j = 0; j < 4; j++) acc[i][j] = z;

    gemm_core_glds(xb, wqkvb, D_, bm, bn, tid, acc, lds_a, lds_b);

    const int n0 = bn * 128;
    const int part = bn / 16;            // 0=q 1=k 2=v (block-uniform)
    const int h = bn & 15;
    const int mb0 = bm * 128 + wm;       // 64-aligned -> one batch, one 64-blk

    if (part < 2) {
        bf16* dst = (part == 0) ? qh : kh;
#pragma unroll
        for (int i = 0; i < 4; i++) {
#pragma unroll
            for (int jp = 0; jp < 2; jp++) {
                const int d1 = wn2 + jp * 16 + lcol;       // 0..63
                const float invf = __expf(-0.14391156831212787f * (float)d1);
                const float b1 = bias[n0 + d1];
                const float b2 = bias[n0 + d1 + 64];
#pragma unroll
                for (int r = 0; r < 4; r++) {
                    const int m = mb0 + i * 16 + quad * 4 + r;
                    const int bb = m >> 11, t = m & (T_ - 1);
                    const float x1 = acc[i][jp][r] + b1;       // d1
                    const float x2 = acc[i][jp + 2][r] + b2;   // d1 + 64
                    float s, c;
                    __sincosf((float)t * invf, &s, &c);
                    const size_t rowo = ((size_t)(bb * H_ + h) * T_ + t) * HD_;
                    dst[rowo + d1]      = (bf16)(x1 * c - x2 * s);
                    dst[rowo + d1 + 64] = (bf16)(x1 * s + x2 * c);
                }
            }
        }
    } else {
        const int bb = mb0 >> 11, t64 = mb0 & (T_ - 1);   // 64-aligned t base
        const int bh = bb * H_ + h;
#pragma unroll
        for (int j = 0; j < 4; j++) {
            const int d = wn2 + (j & 1) * 16 + (j >> 1) * 64 + lcol;
            const float bv = bias[n0 + d];
            bf16* vdst = &vT[((size_t)bh * HD_ + d) * T_ + t64];
#pragma unroll
            for (int r = 0; r < 4; r++) {
                union { bf16 hh[4]; ushort4 u; } pk;
#pragma unroll
                for (int i = 0; i < 4; i++) pk.hh[i] = (bf16)(acc[i][j][r] + bv);
                // phys(t=i*16+quad*4+r) = (quad*4+r)*4 + i  -> contiguous in i
                *(ushort4*)&vdst[(quad * 4 + r) * 4] = pk.u;
            }
        }
    }
}

// ---------------------------------------------------------------------------
// Flash attention (causal), R11: R7 inner loop + uniform 64-row tile PAIRS.
//
// Design-space triangulation (measured):
//   R7:  2 blk/CU + work variance (anti-LPT tail)      -> ~95us
//   R8:  2 blk/CU exact-fit + variance, no backfill    -> ~118us
//   R10: 1 blk/CU + uniform work (no overlap partner)  -> ~133us
// Missing cell = 2 blk/CU + UNIFORM: pair 64-row q-tiles (qt, 31-qt) in one
// block -> steps = (qt+1) + (32-qt) = 33 for every block. Grid = 32bh x 16
// pairs = 512 blocks @ 72KB LDS = exactly 2/CU, zero variance, zero tail.
// Uniformity is what makes exact-fit safe (R8 died of variance, not fit).
// Inner body is R7's verbatim (16 rows/wave, the measured-good per-step
// cost): K+V LDS dbuf via glds16 + XOR swizzle, pi-permuted packed P,
// no-max softmax (p = exp2(s*scale*log2e - 16), shift cancels in o/l),
// diag-only masking, setprio on MFMA clusters. Flat 33-step staging
// sequence continues across the tile switch (dbuf parity unbroken);
// mid-loop epilogue at s==ktA writes tile A, reloads Q, resets acc.
// LDS: 2*16KB (K) + 2*16KB (V) + 8KB (P) = 72KB -> 2 blocks/CU, 8 waves/CU.
// ---------------------------------------------------------------------------
__global__ __launch_bounds__(256) void attn_kernel(
    const bf16* __restrict__ qh, const bf16* __restrict__ kh,
    const bf16* __restrict__ vT, bf16* __restrict__ ctx)
{
    __shared__ bf16 lds_k[2][64 * 128];   // [key][d], XOR-swizzled
    __shared__ bf16 lds_v[2][128 * 64];   // [d][phys-key], XOR-swizzled
    __shared__ bf16 lds_p[64 * 64];       // P (phys-key order), wave-private rows
    const int tid = threadIdx.x;
    const int id = blockIdx.x;            // 512 = 32 bh x 16 pairs
    const int bh = id & 31;
    const int qp = id >> 5;               // 0..15
    const int qtA = 31 - qp;              // heavy tile first (16..31)
    const int qtB = qp;                   // light tile (0..15)
    const int ktA = qtA + 1;              // steps for tile A; ktA+(qtB+1)==33
    const int lane = tid & 63, quad = lane >> 4, lcol = lane & 15;
    const int wave = tid >> 6;
    const int wq0 = wave * 16;
    const float scale2 = 0.08838834764831845f * 1.4426950408889634f;
    const int b = bh >> 4, h = bh & 15;

    const bf16* kbase = kh + (size_t)bh * T_ * HD_;
    const bf16* vbase = vT + (size_t)bh * HD_ * T_;

    // K staging: row srow+16p, chunk tid&15; src col chunk ^ (row&15).
    const int ksrow = tid >> 4;                        // 0..15
    const bf16* kstage = kbase + (size_t)ksrow * HD_ + (((tid & 15) ^ ksrow) << 3);
    // V staging: d row vsd+32p, chunk tid&7; src key chunk ^ (d&7).
    const int vsd = tid >> 3;                          // 0..31
    const bf16* vstage = vbase + (size_t)vsd * T_ + (((tid & 7) ^ (vsd & 7)) << 3);

    int qt_cur = qtA;
    int q0 = qtA * 64;

    bf16x8 qf[4];
    auto load_q = [&](int q0_) {
#pragma unroll
        for (int kk = 0; kk < 4; kk++)
            qf[kk] = *(const bf16x8*)&qh[((size_t)bh * T_ + q0_ + wq0 + lcol) * HD_ +
                                         kk * 32 + quad * 8];
    };
    load_q(q0);

    f32x4 o[8];
    const f32x4 z = {0.f, 0.f, 0.f, 0.f};
#pragma unroll
    for (int jd = 0; jd < 8; jd++) o[jd] = z;
    float l_part[4] = {0.f, 0.f, 0.f, 0.f};

    auto do_epilogue = [&](int q0_) {
        float inv_l[4];
#pragma unroll
        for (int r = 0; r < 4; r++) {
            float rs = l_part[r];
#pragma unroll
            for (int off = 1; off < 16; off <<= 1)
                rs += __shfl_xor(rs, off);
            inv_l[r] = 1.0f / rs;
        }
#pragma unroll
        for (int r = 0; r < 4; r++) {
            const int t = q0_ + wq0 + quad * 4 + r;
#pragma unroll
            for (int jd = 0; jd < 8; jd++)
                ctx[((size_t)(b * T_ + t)) * D_ + h * HD_ + jd * 16 + lcol] =
                    (bf16)(o[jd][r] * inv_l[r]);
        }
    };

    // prologue: stage key-tile 0 into buf 0
#pragma unroll
    for (int p = 0; p < 4; p++) {
        glds16(kstage + (size_t)16 * p * HD_, &lds_k[0][tid * 8 + p * 2048]);
        glds16(vstage + (size_t)32 * p * T_, &lds_v[0][tid * 8 + p * 2048]);
    }

    for (int s = 0; s < 33; s++) {
        __syncthreads();                  // stage(s) landed; buf^1 reads done
        if (s + 1 < 33) {                 // prefetch next key-tile (flat seq)
            const int kn = (s + 1 < ktA) ? (s + 1) : (s + 1 - ktA);
            const bf16* ks = kstage + (size_t)kn * 64 * HD_;
            const bf16* vs = vstage + kn * 64;
            bf16* lkd = &lds_k[(s + 1) & 1][tid * 8];
            bf16* lvd = &lds_v[(s + 1) & 1][tid * 8];
#pragma unroll
            for (int p = 0; p < 4; p++) {
                glds16(ks + (size_t)16 * p * HD_, lkd + p * 2048);
                glds16(vs + (size_t)32 * p * T_, lvd + p * 2048);
            }
        }
        if (s == ktA) {                   // tile switch A -> B (block-uniform)
            do_epilogue(q0);
            qt_cur = qtB;
            q0 = qtB * 64;
            load_q(q0);
#pragma unroll
            for (int jd = 0; jd < 8; jd++) o[jd] = z;
#pragma unroll
            for (int r = 0; r < 4; r++) l_part[r] = 0.f;
        }
        const int kt = (s < ktA) ? s : (s - ktA);
        const bf16* lk = lds_k[s & 1];
        const bf16* lv = lds_v[s & 1];

        // ---- QK^T: K B-fragments from swizzled LDS ----
        f32x4 s_acc[4];
#pragma unroll
        for (int j = 0; j < 4; j++) s_acc[j] = z;
        __builtin_amdgcn_s_setprio(1);
#pragma unroll
        for (int kk = 0; kk < 4; kk++) {
#pragma unroll
            for (int j = 0; j < 4; j++) {
                const bf16x8 bk = *(const bf16x8*)&lk[(j * 16 + lcol) * 128 +
                                        (((kk * 4 + quad) ^ lcol) << 3)];
                s_acc[j] = __builtin_amdgcn_mfma_f32_16x16x32_bf16(qf[kk], bk, s_acc[j], 0, 0, 0);
            }
        }
        __builtin_amdgcn_s_setprio(0);

        // ---- no-max softmax; packed P store in pi-permuted key order ----
        const bool diag = (kt == qt_cur);
#pragma unroll
        for (int r = 0; r < 4; r++) {
            const int prow = wq0 + quad * 4 + r;      // P row (q-local)
            const int qrow = q0 + prow;               // global q row
            union { bf16 hh[4]; ushort4 u; } pk;
            float lp = 0.f;
#pragma unroll
            for (int j = 0; j < 4; j++) {
                float p = exp2f(fmaf(s_acc[j][r], scale2, -16.0f));
                if (diag) {
                    const int kcol = kt * 64 + j * 16 + lcol;
                    p = (kcol > qrow) ? 0.f : p;
                }
                lp += p;
                pk.hh[j] = (bf16)p;      // phys key = lcol*4 + j
            }
            l_part[r] += lp;
            *(ushort4*)&lds_p[prow * 64 + ((lcol * 4) ^ ((prow & 7) << 3))] = pk.u;
        }

        // ---- PV: P and V both from LDS (short, stall-free path) ----
#pragma unroll
        for (int kk2 = 0; kk2 < 2; kk2++) {
            const int prow = wq0 + lcol;
            const bf16x8 pf = *(const bf16x8*)&lds_p[prow * 64 +
                                  ((kk2 * 32 + quad * 8) ^ ((lcol & 7) << 3))];
            bf16x8 vf[8];
#pragma unroll
            for (int jd = 0; jd < 8; jd++) {
                const int d = jd * 16 + lcol;
                vf[jd] = *(const bf16x8*)&lv[d * 64 +
                              (((kk2 * 4 + quad) ^ (lcol & 7)) << 3)];
            }
            __builtin_amdgcn_s_setprio(1);
#pragma unroll
            for (int jd = 0; jd < 8; jd++)
                o[jd] = __builtin_amdgcn_mfma_f32_16x16x32_bf16(pf, vf[jd], o[jd], 0, 0, 0);
            __builtin_amdgcn_s_setprio(0);
        }
    }

    do_epilogue(q0);                      // tile B epilogue
}

// ---------------------------------------------------------------------------
// Output projection: out = ctx @ Wo^T + bo  (bf16 x bf16 -> fp32 out)
// ---------------------------------------------------------------------------
__global__ __launch_bounds__(256) void proj_gemm_kernel(
    const bf16* __restrict__ ctx, const bf16* __restrict__ wob,
    const float* __restrict__ bias, float* __restrict__ out)
{
    __shared__ bf16 lds_a[128 * 64];
    __shared__ bf16 lds_b[128 * 64];
    const int tid = threadIdx.x;
    const int bm = blockIdx.y, bn = blockIdx.x;
    const int lane = tid & 63, quad = lane >> 4, lcol = lane & 15;
    const int wave = tid >> 6;
    const int wm = (wave >> 1) * 64, wn2 = (wave & 1) * 32;

    f32x4 acc[4][4];
    const f32x4 z = {0.f, 0.f, 0.f, 0.f};
#pragma unroll
    for (int i = 0; i < 4; i++)
#pragma unroll
        for (int j = 0; j < 4; j++) acc[i][j] = z;

    gemm_core_glds(ctx, wob, D_, bm, bn, tid, acc, lds_a, lds_b);

    const int n0 = bn * 128;
#pragma unroll
    for (int i = 0; i < 4; i++) {
#pragma unroll
        for (int j = 0; j < 4; j++) {
            const int n = n0 + wn2 + (j & 1) * 16 + (j >> 1) * 64 + lcol;
            const float bv = bias[n];
#pragma unroll
            for (int r = 0; r < 4; r++) {
                const int m = bm * 128 + wm + i * 16 + quad * 4 + r;
                out[(size_t)m * D_ + n] = acc[i][j][r] + bv;
            }
        }
    }
}

extern "C" void kernel_launch(void* const* d_in, const int* in_sizes, int n_in,
                              void* d_out, int out_size, void* d_ws, size_t ws_size,
                              hipStream_t stream)
{
    const float* x    = (const float*)d_in[0];
    const float* Wqkv = (const float*)d_in[1];
    const float* bqkv = (const float*)d_in[2];
    const float* Wo   = (const float*)d_in[3];
    const float* bo   = (const float*)d_in[4];
    // d_in[5] = mask — causal, computed analytically in-kernel.
    float* out = (float*)d_out;

    const size_t HT = (size_t)B_ * H_ * T_ * HD_;   // 8,388,608 elems
    // d_ws (67.1 MB, proven size): [xb|ctx][qh|wob][kh][vT]
    bf16* xb   = (bf16*)d_ws;
    bf16* qh   = xb + HT;
    bf16* kh   = qh + HT;
    bf16* vT   = kh + HT;
    bf16* ctx  = xb;             // xb dead after qkv gemm
    bf16* wob  = qh;             // qh dead after attn
    // d_out (33.55 MB fp32): holds bf16 Wqkv (25.2 MB) until proj overwrites
    bf16* wqkvb = (bf16*)d_out;

    // 1) fp32 -> bf16 pre-convert of x and Wqkv
    convert_xw_kernel<<<2560, 256, 0, stream>>>(x, Wqkv, xb, wqkvb);
    // 2) QKV projection + fused RoPE + head scatter (vT pi-permuted keys)
    qkv_gemm_kernel<<<dim3(48, 32), 256, 0, stream>>>(xb, wqkvb, bqkv, qh, kh, vT);
    // 3) causal flash attention -> ctx: 512 uniform blocks, each = 64-row
    //    q-tile pair (qt, 31-qt) => 33 key-tile steps, 2 blocks/CU, no tail
    attn_kernel<<<512, 256, 0, stream>>>(qh, kh, vT, ctx);
    // 4) Wo -> bf16 into dead qh region
    convert_wo_kernel<<<1024, 256, 0, stream>>>(Wo, wob);
    // 5) output projection -> fp32 out (overwrites wqkvb region)
    proj_gemm_kernel<<<dim3(16, 32), 256, 0, stream>>>(ctx, wob, bo, out);
}